// Round 6
// baseline (54.533 us; speedup 1.0000x reference)
//
#include <hip/hip_runtime.h>
#include <hip/hip_bf16.h>
#include <cmath>
#include <complex>

// ---------------- static problem config ----------------
#define NDIM1 576
#define NDIM2 9
#define NDIMO 576
#define ROWB 2304            // bytes per x1 row (576 f32)
#define TILEB 36864          // 16 rows * 2304 B
#define TPB 4                // tiles per block (grid-stride pipeline depth)

typedef __attribute__((ext_vector_type(8))) short short8;
typedef __attribute__((ext_vector_type(4))) float f32x4;

struct CGTab { float v[363]; };

union U8 { unsigned short s[8]; short8 v; };

__device__ inline unsigned short f2bf(float x) {
  return __builtin_bit_cast(unsigned short, __float2bfloat16(x));
}

// real-basis CG selection rule (superset of nonzeros):
constexpr bool cg_nonzero(int m1, int m2, int m3) {
  int a1 = m1 < 0 ? -m1 : m1, a2 = m2 < 0 ? -m2 : m2, a3 = m3 < 0 ? -m3 : m3;
  int d = a1 > a2 ? a1 - a2 : a2 - a1;
  bool mag = (a3 == a1 + a2) || (a3 == d);
  int neg = (m1 < 0) + (m2 < 0) + (m3 < 0);
  return mag && ((neg & 1) == 0);
}

// ---------------- prep kernel: pack W into bf16 MFMA B-fragments ----------------
__global__ __launch_bounds__(256) void prep_w_kernel(const float* __restrict__ W,
                                                     short8* __restrict__ wf) {
  int idx = blockIdx.x * 256 + threadIdx.x;
  if (idx >= 11 * 2 * 4 * 64) return;
  int lane = idx & 63;
  int v = (idx >> 6) & 3;
  int s = (idx >> 8) & 1;
  int p = idx >> 9;
  int g = lane >> 4, r16 = lane & 15;
  const float* wp = W + p * 4096 + (s * 32 + g * 8) * 64 + v * 16 + r16;
  U8 u;
#pragma unroll
  for (int t = 0; t < 8; t++) u.s[t] = f2bf(wp[t * 64]);
  wf[idx] = u.v;
}

// ---------------- device helpers ----------------
typedef __attribute__((address_space(1))) const unsigned int gu32;
typedef __attribute__((address_space(3))) unsigned int lu32;

// read one i1-chunk's raw f32 data from swizzled LDS tile
template <int NI, int OFFB>  // OFFB = chunk float offset * 4 (bytes)
__device__ inline void load_lds_chunk(const char* tilebase, int g, int r16,
                                      f32x4 (&raw)[4 * NI]) {
  const char* rowp = tilebase + r16 * ROWB;
  const int rowx = (r16 & 7) << 4;
#pragma unroll
  for (int s = 0; s < 2; s++) {
#pragma unroll
    for (int q = 0; q < 2 * NI; q++) {
      int cb = OFFB + ((s * 32 + g * 8) * NI) * 4 + q * 16;
      raw[s * 2 * NI + q] = *(const f32x4*)(rowp + (cb ^ rowx));
    }
  }
}

template <int NI>
__device__ inline void convert_x1(const f32x4 (&raw)[4 * NI], short8 (&af)[NI][2]) {
#pragma unroll
  for (int s = 0; s < 2; s++) {
#pragma unroll
    for (int i = 0; i < NI; i++) {
      U8 u;
#pragma unroll
      for (int t = 0; t < 8; t++) {
        int idx = t * NI + i;
        u.s[t] = f2bf(raw[s * 2 * NI + (idx >> 2)][idx & 3]);
      }
      af[i][s] = u.v;
    }
  }
}

template <int NI>
__device__ inline void run_path(const short8* __restrict__ wf, int p, int v, int lane,
                                const short8 (&af)[NI][2], f32x4 (&acc)[NI]) {
#pragma unroll
  for (int i = 0; i < NI; i++) acc[i] = (f32x4){0.f, 0.f, 0.f, 0.f};
#pragma unroll
  for (int s = 0; s < 2; s++) {
    short8 b = wf[((p * 2 + s) * 4 + v) * 64 + lane];
#pragma unroll
    for (int i = 0; i < NI; i++)
      acc[i] = __builtin_amdgcn_mfma_f32_16x16x32_bf16(af[i][s], b, acc[i], 0, 0, 0);
  }
}

template <int L1, int L2, int LO, int CGO, int NI>
__device__ inline void epilogue(const float* __restrict__ cg, const f32x4 (&acc)[NI],
                                const float (&x2v)[4][9], float (&outr)[4][9]) {
  constexpr int JO = (L2 == 0) ? 0 : (L2 == 1 ? 1 : 4);
  constexpr int KO = (LO == 0) ? 0 : (LO == 1 ? 1 : 4);
#pragma unroll
  for (int i = 0; i < 2 * L1 + 1; i++) {
#pragma unroll
    for (int j = 0; j < 2 * L2 + 1; j++) {
#pragma unroll
      for (int k = 0; k < 2 * LO + 1; k++) {
        if (!cg_nonzero(i - L1, j - L2, k - LO)) continue;  // folds after unroll
        float c = cg[CGO + (i * (2 * L2 + 1) + j) * (2 * LO + 1) + k];
#pragma unroll
        for (int r = 0; r < 4; r++)
          outr[r][KO + k] = fmaf(c * x2v[r][JO + j], acc[i][r], outr[r][KO + k]);
      }
    }
  }
}

// ---------------- main kernel ----------------
// Grid-stride pipeline: block owns TPB consecutive 16-row tiles, double-
// buffered LDS. Per iter: issue next tile's 9 global_load_lds, counted
// s_waitcnt vmcnt(9) (keeps the prefetch in flight), raw barrier, compute,
// second barrier before the buffer gets overwritten next iteration.
__global__ __launch_bounds__(256) void TPWithWeights_44925357916441_kernel(
    const float* __restrict__ x1, const float* __restrict__ x2,
    const short8* __restrict__ wf, float* __restrict__ out, CGTab tab) {
  __shared__ float tile[2][TILEB / 4];

  const int lane = threadIdx.x & 63;
  const int v = threadIdx.x >> 6;   // wave id -> w sub-tile
  const int g = lane >> 4, r16 = lane & 15;
  const int t0 = blockIdx.x * TPB;  // first tile of this block
  const float* cg = tab.v;

  // stage tile nt into LDS buffer b (9 chunks of 1KB per wave, 36 total)
  auto stage = [&](int nt, int b) {
    const char* x1base = (const char*)(x1 + (size_t)(nt << 4) * NDIM1);
#pragma unroll
    for (int ch = 0; ch < 9; ch++) {
      const int c = v * 9 + ch;
      const int P = c * 1024 + lane * 16;       // physical LDS byte this lane fills
      const int row = P / ROWB;                 // logical row
      const int rem = P - row * ROWB;           // logical col-byte (linear)
      const int sb = rem ^ ((row & 7) << 4);    // inverse-swizzle source (XOR involution)
      __builtin_amdgcn_global_load_lds((gu32*)(x1base + row * ROWB + sb),
                                       (lu32*)(&tile[b][0] + c * 256), 16, 0, 0);
    }
  };

  stage(t0, 0);  // prologue

  for (int t = 0; t < TPB; t++) {
    const int n0 = (t0 + t) << 4;
    const int cur = t & 1;

    if (t + 1 < TPB) stage(t0 + t + 1, cur ^ 1);

    // wait: everything older than the 9 just-issued prefetch loads (i.e. this
    // tile's staging + previous stores) is complete; prefetch stays in flight.
    asm volatile("s_waitcnt vmcnt(9)" ::: "memory");
    __builtin_amdgcn_sched_barrier(0);
    __builtin_amdgcn_s_barrier();
    __builtin_amdgcn_sched_barrier(0);

    // ---- x2 for this lane's 4 rows ----
    f32x4 xv[9];
    {
      const f32x4* p2 = (const f32x4*)(x2 + (size_t)(n0 + g * 4) * NDIM2);
#pragma unroll
      for (int q = 0; q < 9; q++) xv[q] = p2[q];
    }
    float x2v[4][9];
    float outr[4][9];
#pragma unroll
    for (int r = 0; r < 4; r++)
#pragma unroll
      for (int j = 0; j < 9; j++) {
        int idx = r * 9 + j;
        x2v[r][j] = xv[idx >> 2][idx & 3];
        outr[r][j] = 0.f;
      }

    const char* tb = (const char*)&tile[cur][0];

    {  // chunk i1=0 (l1=0), paths 0..2
      f32x4 raw[4]; short8 af[1][2]; f32x4 acc[1];
      load_lds_chunk<1, 0>(tb, g, r16, raw);
      convert_x1<1>(raw, af);
      run_path<1>(wf, 0, v, lane, af, acc); epilogue<0, 0, 0, 0, 1>(cg, acc, x2v, outr);
      run_path<1>(wf, 1, v, lane, af, acc); epilogue<0, 1, 1, 1, 1>(cg, acc, x2v, outr);
      run_path<1>(wf, 2, v, lane, af, acc); epilogue<0, 2, 2, 10, 1>(cg, acc, x2v, outr);
    }
    {  // chunk i1=1 (l1=1), paths 3..6
      f32x4 raw[12]; short8 af[3][2]; f32x4 acc[3];
      load_lds_chunk<3, 256>(tb, g, r16, raw);
      convert_x1<3>(raw, af);
      run_path<3>(wf, 3, v, lane, af, acc); epilogue<1, 0, 1, 35, 3>(cg, acc, x2v, outr);
      run_path<3>(wf, 4, v, lane, af, acc); epilogue<1, 1, 0, 44, 3>(cg, acc, x2v, outr);
      run_path<3>(wf, 5, v, lane, af, acc); epilogue<1, 1, 2, 53, 3>(cg, acc, x2v, outr);
      run_path<3>(wf, 6, v, lane, af, acc); epilogue<1, 2, 1, 98, 3>(cg, acc, x2v, outr);
    }
    {  // chunk i1=2 (l1=2), paths 7..10
      f32x4 raw[20]; short8 af[5][2]; f32x4 acc[5];
      load_lds_chunk<5, 1024>(tb, g, r16, raw);
      convert_x1<5>(raw, af);
      run_path<5>(wf, 7, v, lane, af, acc); epilogue<2, 0, 2, 143, 5>(cg, acc, x2v, outr);
      run_path<5>(wf, 8, v, lane, af, acc); epilogue<2, 1, 1, 168, 5>(cg, acc, x2v, outr);
      run_path<5>(wf, 9, v, lane, af, acc); epilogue<2, 2, 0, 213, 5>(cg, acc, x2v, outr);
      run_path<5>(wf, 10, v, lane, af, acc); epilogue<2, 2, 2, 238, 5>(cg, acc, x2v, outr);
    }

    const int w = v * 16 + r16;
#pragma unroll
    for (int r = 0; r < 4; r++) {
      float* op = out + (size_t)(n0 + g * 4 + r) * NDIMO;
      op[w] = outr[r][0];
#pragma unroll
      for (int k = 0; k < 3; k++) op[64 + w * 3 + k] = outr[r][1 + k];
#pragma unroll
      for (int k = 0; k < 5; k++) op[256 + w * 5 + k] = outr[r][4 + k];
    }

    // all waves done reading tile[cur] before next iter overwrites it
    __builtin_amdgcn_sched_barrier(0);
    __builtin_amdgcn_s_barrier();
    __builtin_amdgcn_sched_barrier(0);
  }
}

// ---------------- host: exact port of reference CG computation ----------------
static double h_fact(int n) { double r = 1.0; for (int i = 2; i <= n; i++) r *= (double)i; return r; }
static inline int imax3(int a, int b, int c) { int m = a > b ? a : b; return m > c ? m : c; }
static inline int imin3(int a, int b, int c) { int m = a < b ? a : b; return m < c ? m : c; }

static double su2_cg(int j1, int m1, int j2, int m2, int j3, int m3) {
  if (m3 != m1 + m2) return 0.0;
  int vmin = imax3(-j1 + j2 + m3, -j1 + m1, 0);
  int vmax = imin3(j2 + j3 + m1, j3 - j1 + j2, j3 + m3);
  double C = sqrt((2.0 * j3 + 1.0) * h_fact(j3 + j1 - j2) * h_fact(j3 - j1 + j2) *
                  h_fact(j1 + j2 - j3) * h_fact(j3 + m3) * h_fact(j3 - m3) /
                  (h_fact(j1 + j2 + j3 + 1) * h_fact(j1 - m1) * h_fact(j1 + m1) *
                   h_fact(j2 - m2) * h_fact(j2 + m2)));
  double S = 0.0;
  for (int vv = vmin; vv <= vmax; vv++) {
    double sg = ((vv + j2 + m2) & 1) ? -1.0 : 1.0;
    S += sg * h_fact(j2 + j3 + m1 - vv) * h_fact(j1 - m1 + vv) /
         (h_fact(vv) * h_fact(j3 - j1 + j2 - vv) * h_fact(j3 + m3 - vv) * h_fact(vv + j1 - j2 - m3));
  }
  return C * S;
}

static void cb_r2c(int l, std::complex<double> q[5][5]) {
  for (int a = 0; a < 5; a++) for (int b = 0; b < 5; b++) q[a][b] = 0.0;
  const double is2 = 1.0 / sqrt(2.0);
  for (int m = -l; m < 0; m++) {
    q[l + m][l - m] = is2;
    q[l + m][l + m] = std::complex<double>(0.0, -is2);
  }
  q[l][l] = 1.0;
  for (int m = 1; m <= l; m++) {
    double sg = (m & 1) ? -1.0 : 1.0;
    q[l + m][l + m] = sg * is2;
    q[l + m][l - m] = std::complex<double>(0.0, sg * is2);
  }
  std::complex<double> f(1.0, 0.0);
  for (int t = 0; t < l; t++) f *= std::complex<double>(0.0, -1.0);
  for (int a = 0; a < 2 * l + 1; a++) for (int b = 0; b < 2 * l + 1; b++) q[a][b] *= f;
}

static void cg_real(int l1, int l2, int l3, double outm[5][5][5]) {
  std::complex<double> q1[5][5], q2[5][5], q3[5][5];
  cb_r2c(l1, q1); cb_r2c(l2, q2); cb_r2c(l3, q3);
  double nrm = 0.0;
  for (int x = 0; x < 2 * l1 + 1; x++)
    for (int y = 0; y < 2 * l2 + 1; y++)
      for (int z = 0; z < 2 * l3 + 1; z++) {
        std::complex<double> a(0.0, 0.0);
        for (int i = 0; i < 2 * l1 + 1; i++)
          for (int k = 0; k < 2 * l2 + 1; k++)
            for (int n = 0; n < 2 * l3 + 1; n++) {
              double s = su2_cg(l1, i - l1, l2, k - l2, l3, n - l3);
              if (s != 0.0) a += q1[i][x] * q2[k][y] * std::conj(q3[n][z]) * s;
            }
        outm[x][y][z] = a.real();
        nrm += a.real() * a.real();
      }
  nrm = sqrt(nrm);
  for (int x = 0; x < 2 * l1 + 1; x++)
    for (int y = 0; y < 2 * l2 + 1; y++)
      for (int z = 0; z < 2 * l3 + 1; z++) outm[x][y][z] /= nrm;
}

static void build_cg_tables(CGTab& tab) {
  const int PL1[11] = {0, 0, 0, 1, 1, 1, 1, 2, 2, 2, 2};
  const int PL2[11] = {0, 1, 2, 0, 1, 1, 2, 0, 1, 2, 2};
  const int PLO[11] = {0, 1, 2, 1, 0, 2, 1, 2, 1, 0, 2};
  const int CGO[11] = {0, 1, 10, 35, 44, 53, 98, 143, 168, 213, 238};
  const double pw_io[3] = {sqrt(1.0 / 192.0), sqrt(3.0 / 256.0), sqrt(5.0 / 256.0)};
  for (int p = 0; p < 11; p++) {
    int l1 = PL1[p], l2 = PL2[p], lo = PLO[p];
    double c[5][5][5];
    cg_real(l1, l2, lo, c);
    double pw = pw_io[lo];
    for (int i = 0; i < 2 * l1 + 1; i++)
      for (int j = 0; j < 2 * l2 + 1; j++)
        for (int k = 0; k < 2 * lo + 1; k++)
          tab.v[CGO[p] + (i * (2 * l2 + 1) + j) * (2 * lo + 1) + k] = (float)(pw * c[i][j][k]);
  }
}

// ---------------- launch ----------------
extern "C" void kernel_launch(void* const* d_in, const int* in_sizes, int n_in,
                              void* d_out, int out_size, void* d_ws, size_t ws_size,
                              hipStream_t stream) {
  const float* x1 = (const float*)d_in[0];
  const float* x2 = (const float*)d_in[1];
  const float* W  = (const float*)d_in[2];
  float* out = (float*)d_out;

  int N = in_sizes[0] / NDIM1;  // 32768

  CGTab tab;
  build_cg_tables(tab);  // deterministic host-side computation, ~µs

  short8* wf = (short8*)d_ws;  // 11*2*4*64 * 16B = 90112 B

  hipLaunchKernelGGL(prep_w_kernel, dim3(22), dim3(256), 0, stream, W, wf);
  hipLaunchKernelGGL(TPWithWeights_44925357916441_kernel, dim3(N / (16 * TPB)), dim3(256), 0,
                     stream, x1, x2, wf, out, tab);
}

// Round 7
// 49.915 us; speedup vs baseline: 1.0925x; 1.0925x over previous
//
#include <hip/hip_runtime.h>
#include <hip/hip_bf16.h>
#include <cmath>
#include <complex>

// ---------------- static problem config ----------------
#define NDIM1 576
#define NDIM2 9
#define NDIMO 576

typedef __attribute__((ext_vector_type(8))) short short8;
typedef __attribute__((ext_vector_type(4))) float f32x4;

struct CGTab { float v[363]; };

union U8 { unsigned short s[8]; short8 v; };

__device__ inline unsigned short f2bf(float x) {
  return __builtin_bit_cast(unsigned short, __float2bfloat16(x));
}

// real-basis CG selection rule (superset of nonzeros):
constexpr bool cg_nonzero(int m1, int m2, int m3) {
  int a1 = m1 < 0 ? -m1 : m1, a2 = m2 < 0 ? -m2 : m2, a3 = m3 < 0 ? -m3 : m3;
  int d = a1 > a2 ? a1 - a2 : a2 - a1;
  bool mag = (a3 == a1 + a2) || (a3 == d);
  int neg = (m1 < 0) + (m2 < 0) + (m3 < 0);
  return mag && ((neg & 1) == 0);
}

// ---------------- prep kernel: pack W into bf16 MFMA B-fragments ----------------
__global__ __launch_bounds__(256) void prep_w_kernel(const float* __restrict__ W,
                                                     short8* __restrict__ wf) {
  int idx = blockIdx.x * 256 + threadIdx.x;
  if (idx >= 11 * 2 * 4 * 64) return;
  int lane = idx & 63;
  int v = (idx >> 6) & 3;
  int s = (idx >> 8) & 1;
  int p = idx >> 9;
  int g = lane >> 4, r16 = lane & 15;
  const float* wp = W + p * 4096 + (s * 32 + g * 8) * 64 + v * 16 + r16;
  U8 u;
#pragma unroll
  for (int t = 0; t < 8; t++) u.s[t] = f2bf(wp[t * 64]);
  wf[idx] = u.v;
}

// ---------------- staging: global f32 -> registers (issue-early) ----------------
// wave roles: wv0 = chunk0 (c0), wv1 = chunk1 (c1), wv2/wv3 = chunk2 s=0/1.
// Each lane loads the contiguous span containing its (g, r16) frag elements.
__device__ __forceinline__ void stage_issue(const float* __restrict__ x1, int nt,
                                            int wv, int g, int r16, f32x4 (&raw)[12]) {
  const float* row = x1 + (size_t)(nt * 16 + r16) * NDIM1;
  if (wv == 0) {            // c0: two 8-float spans (s=0,1)
#pragma unroll
    for (int s = 0; s < 2; s++) {
      const f32x4* p = (const f32x4*)(row + (s * 32 + g * 8));
      raw[s * 2 + 0] = p[0];
      raw[s * 2 + 1] = p[1];
    }
  } else if (wv == 1) {     // c1: two 24-float spans
#pragma unroll
    for (int s = 0; s < 2; s++) {
      const f32x4* p = (const f32x4*)(row + 64 + (s * 32 + g * 8) * 3);
#pragma unroll
      for (int q = 0; q < 6; q++) raw[s * 6 + q] = p[q];
    }
  } else {                  // c2: one 40-float span (s = wv-2)
    const int s = wv - 2;
    const f32x4* p = (const f32x4*)(row + 256 + (s * 32 + g * 8) * 5);
#pragma unroll
    for (int q = 0; q < 10; q++) raw[q] = p[q];
  }
}

// convert + write bf16 frags into LDS buffer fb[f][lane] (write-late)
__device__ __forceinline__ void stage_write(short8 (*fb)[64], int wv, int lane,
                                            const f32x4 (&raw)[12]) {
  const float* rf = (const float*)raw;
  if (wv == 0) {
#pragma unroll
    for (int s = 0; s < 2; s++) {
      U8 u;
#pragma unroll
      for (int t = 0; t < 8; t++) u.s[t] = f2bf(rf[s * 8 + t]);
      fb[s][lane] = u.v;
    }
  } else if (wv == 1) {
#pragma unroll
    for (int s = 0; s < 2; s++)
#pragma unroll
      for (int i = 0; i < 3; i++) {
        U8 u;
#pragma unroll
        for (int t = 0; t < 8; t++) u.s[t] = f2bf(rf[s * 24 + t * 3 + i]);
        fb[2 + s * 3 + i][lane] = u.v;
      }
  } else {
    const int s = wv - 2;
#pragma unroll
    for (int i = 0; i < 5; i++) {
      U8 u;
#pragma unroll
      for (int t = 0; t < 8; t++) u.s[t] = f2bf(rf[t * 5 + i]);
      fb[8 + s * 5 + i][lane] = u.v;
    }
  }
}

// ---------------- MFMA + epilogue ----------------
template <int NI>
__device__ __forceinline__ void run_path(const short8* __restrict__ wf, int p, int v, int lane,
                                         const short8 (&af)[NI][2], f32x4 (&acc)[NI]) {
#pragma unroll
  for (int i = 0; i < NI; i++) acc[i] = (f32x4){0.f, 0.f, 0.f, 0.f};
#pragma unroll
  for (int s = 0; s < 2; s++) {
    short8 b = wf[((p * 2 + s) * 4 + v) * 64 + lane];
#pragma unroll
    for (int i = 0; i < NI; i++)
      acc[i] = __builtin_amdgcn_mfma_f32_16x16x32_bf16(af[i][s], b, acc[i], 0, 0, 0);
  }
}

template <int L1, int L2, int LO, int CGO, int NI>
__device__ __forceinline__ void epilogue(const float* __restrict__ cg, const f32x4 (&acc)[NI],
                                         const float (&x2v)[4][9], float (&outr)[4][9]) {
  constexpr int JO = (L2 == 0) ? 0 : (L2 == 1 ? 1 : 4);
  constexpr int KO = (LO == 0) ? 0 : (LO == 1 ? 1 : 4);
#pragma unroll
  for (int i = 0; i < 2 * L1 + 1; i++) {
#pragma unroll
    for (int j = 0; j < 2 * L2 + 1; j++) {
#pragma unroll
      for (int k = 0; k < 2 * LO + 1; k++) {
        if (!cg_nonzero(i - L1, j - L2, k - LO)) continue;  // folds after unroll
        float c = cg[CGO + (i * (2 * L2 + 1) + j) * (2 * LO + 1) + k];
#pragma unroll
        for (int r = 0; r < 4; r++)
          outr[r][KO + k] = fmaf(c * x2v[r][JO + j], acc[i][r], outr[r][KO + k]);
      }
    }
  }
}

// full compute for one 16-row tile from a staged bf16-frag buffer
__device__ __forceinline__ void compute_tile(const short8 (*fb)[64],
                                             const float* __restrict__ x2,
                                             const short8* __restrict__ wf,
                                             float* __restrict__ out,
                                             const float* __restrict__ cg,
                                             int n0, int v, int lane, int g, int r16) {
  // x2 for this lane's 4 rows
  f32x4 xv[9];
  {
    const f32x4* p2 = (const f32x4*)(x2 + (size_t)(n0 + g * 4) * NDIM2);
#pragma unroll
    for (int q = 0; q < 9; q++) xv[q] = p2[q];
  }
  float x2v[4][9];
  float outr[4][9];
#pragma unroll
  for (int r = 0; r < 4; r++)
#pragma unroll
    for (int j = 0; j < 9; j++) {
      int idx = r * 9 + j;
      x2v[r][j] = xv[idx >> 2][idx & 3];
      outr[r][j] = 0.f;
    }

  {  // chunk0 (l1=0), paths 0..2
    short8 af[1][2]; f32x4 acc[1];
#pragma unroll
    for (int s = 0; s < 2; s++) af[0][s] = fb[s][lane];
    run_path<1>(wf, 0, v, lane, af, acc); epilogue<0, 0, 0, 0, 1>(cg, acc, x2v, outr);
    run_path<1>(wf, 1, v, lane, af, acc); epilogue<0, 1, 1, 1, 1>(cg, acc, x2v, outr);
    run_path<1>(wf, 2, v, lane, af, acc); epilogue<0, 2, 2, 10, 1>(cg, acc, x2v, outr);
  }
  {  // chunk1 (l1=1), paths 3..6
    short8 af[3][2]; f32x4 acc[3];
#pragma unroll
    for (int s = 0; s < 2; s++)
#pragma unroll
      for (int i = 0; i < 3; i++) af[i][s] = fb[2 + s * 3 + i][lane];
    run_path<3>(wf, 3, v, lane, af, acc); epilogue<1, 0, 1, 35, 3>(cg, acc, x2v, outr);
    run_path<3>(wf, 4, v, lane, af, acc); epilogue<1, 1, 0, 44, 3>(cg, acc, x2v, outr);
    run_path<3>(wf, 5, v, lane, af, acc); epilogue<1, 1, 2, 53, 3>(cg, acc, x2v, outr);
    run_path<3>(wf, 6, v, lane, af, acc); epilogue<1, 2, 1, 98, 3>(cg, acc, x2v, outr);
  }
  {  // chunk2 (l1=2), paths 7..10
    short8 af[5][2]; f32x4 acc[5];
#pragma unroll
    for (int s = 0; s < 2; s++)
#pragma unroll
      for (int i = 0; i < 5; i++) af[i][s] = fb[8 + s * 5 + i][lane];
    run_path<5>(wf, 7, v, lane, af, acc); epilogue<2, 0, 2, 143, 5>(cg, acc, x2v, outr);
    run_path<5>(wf, 8, v, lane, af, acc); epilogue<2, 1, 1, 168, 5>(cg, acc, x2v, outr);
    run_path<5>(wf, 9, v, lane, af, acc); epilogue<2, 2, 0, 213, 5>(cg, acc, x2v, outr);
    run_path<5>(wf, 10, v, lane, af, acc); epilogue<2, 2, 2, 238, 5>(cg, acc, x2v, outr);
  }

  const int w = v * 16 + r16;
#pragma unroll
  for (int r = 0; r < 4; r++) {
    float* op = out + (size_t)(n0 + g * 4 + r) * NDIMO;
    op[w] = outr[r][0];
#pragma unroll
    for (int k = 0; k < 3; k++) op[64 + w * 3 + k] = outr[r][1 + k];
#pragma unroll
    for (int k = 0; k < 5; k++) op[256 + w * 5 + k] = outr[r][4 + k];
  }
}

// ---------------- main kernel ----------------
// Block = 2 tiles of 16 rows, 4 waves. Staging: reg-stage f32 -> bf16 frags
// into LDS (convert ONCE per element; frag transpose at staging). Double
// buffer (2 x 18.4 KB = 36.9 KB -> 4 blocks/CU). T14 split: issue tile-1
// loads early, compute tile 0, convert+write tile 1, one barrier per tile.
__global__ __launch_bounds__(256) void TPWithWeights_44925357916441_kernel(
    const float* __restrict__ x1, const float* __restrict__ x2,
    const short8* __restrict__ wf, float* __restrict__ out, CGTab tab) {
  __shared__ short8 frg[2][18][64];

  const int lane = threadIdx.x & 63;
  const int wv = threadIdx.x >> 6;   // wave id: staging role AND w sub-tile v
  const int g = lane >> 4, r16 = lane & 15;
  const int t0 = blockIdx.x * 2;
  const float* cg = tab.v;

  // prologue: stage tile 0
  {
    f32x4 rawA[12];
    stage_issue(x1, t0, wv, g, r16, rawA);
    stage_write(frg[0], wv, lane, rawA);
  }
  __syncthreads();

  // t=0: issue tile-1 loads early, compute tile 0, write tile-1 frags late
  {
    f32x4 rawB[12];
    stage_issue(x1, t0 + 1, wv, g, r16, rawB);
    compute_tile(frg[0], x2, wf, out, cg, t0 << 4, wv, lane, g, r16);
    stage_write(frg[1], wv, lane, rawB);
  }
  __syncthreads();

  // t=1: compute tile 1
  compute_tile(frg[1], x2, wf, out, cg, (t0 + 1) << 4, wv, lane, g, r16);
}

// ---------------- host: exact port of reference CG computation ----------------
static double h_fact(int n) { double r = 1.0; for (int i = 2; i <= n; i++) r *= (double)i; return r; }
static inline int imax3(int a, int b, int c) { int m = a > b ? a : b; return m > c ? m : c; }
static inline int imin3(int a, int b, int c) { int m = a < b ? a : b; return m < c ? m : c; }

static double su2_cg(int j1, int m1, int j2, int m2, int j3, int m3) {
  if (m3 != m1 + m2) return 0.0;
  int vmin = imax3(-j1 + j2 + m3, -j1 + m1, 0);
  int vmax = imin3(j2 + j3 + m1, j3 - j1 + j2, j3 + m3);
  double C = sqrt((2.0 * j3 + 1.0) * h_fact(j3 + j1 - j2) * h_fact(j3 - j1 + j2) *
                  h_fact(j1 + j2 - j3) * h_fact(j3 + m3) * h_fact(j3 - m3) /
                  (h_fact(j1 + j2 + j3 + 1) * h_fact(j1 - m1) * h_fact(j1 + m1) *
                   h_fact(j2 - m2) * h_fact(j2 + m2)));
  double S = 0.0;
  for (int vv = vmin; vv <= vmax; vv++) {
    double sg = ((vv + j2 + m2) & 1) ? -1.0 : 1.0;
    S += sg * h_fact(j2 + j3 + m1 - vv) * h_fact(j1 - m1 + vv) /
         (h_fact(vv) * h_fact(j3 - j1 + j2 - vv) * h_fact(j3 + m3 - vv) * h_fact(vv + j1 - j2 - m3));
  }
  return C * S;
}

static void cb_r2c(int l, std::complex<double> q[5][5]) {
  for (int a = 0; a < 5; a++) for (int b = 0; b < 5; b++) q[a][b] = 0.0;
  const double is2 = 1.0 / sqrt(2.0);
  for (int m = -l; m < 0; m++) {
    q[l + m][l - m] = is2;
    q[l + m][l + m] = std::complex<double>(0.0, -is2);
  }
  q[l][l] = 1.0;
  for (int m = 1; m <= l; m++) {
    double sg = (m & 1) ? -1.0 : 1.0;
    q[l + m][l + m] = sg * is2;
    q[l + m][l - m] = std::complex<double>(0.0, sg * is2);
  }
  std::complex<double> f(1.0, 0.0);
  for (int t = 0; t < l; t++) f *= std::complex<double>(0.0, -1.0);
  for (int a = 0; a < 2 * l + 1; a++) for (int b = 0; b < 2 * l + 1; b++) q[a][b] *= f;
}

static void cg_real(int l1, int l2, int l3, double outm[5][5][5]) {
  std::complex<double> q1[5][5], q2[5][5], q3[5][5];
  cb_r2c(l1, q1); cb_r2c(l2, q2); cb_r2c(l3, q3);
  double nrm = 0.0;
  for (int x = 0; x < 2 * l1 + 1; x++)
    for (int y = 0; y < 2 * l2 + 1; y++)
      for (int z = 0; z < 2 * l3 + 1; z++) {
        std::complex<double> a(0.0, 0.0);
        for (int i = 0; i < 2 * l1 + 1; i++)
          for (int k = 0; k < 2 * l2 + 1; k++)
            for (int n = 0; n < 2 * l3 + 1; n++) {
              double s = su2_cg(l1, i - l1, l2, k - l2, l3, n - l3);
              if (s != 0.0) a += q1[i][x] * q2[k][y] * std::conj(q3[n][z]) * s;
            }
        outm[x][y][z] = a.real();
        nrm += a.real() * a.real();
      }
  nrm = sqrt(nrm);
  for (int x = 0; x < 2 * l1 + 1; x++)
    for (int y = 0; y < 2 * l2 + 1; y++)
      for (int z = 0; z < 2 * l3 + 1; z++) outm[x][y][z] /= nrm;
}

static void build_cg_tables(CGTab& tab) {
  const int PL1[11] = {0, 0, 0, 1, 1, 1, 1, 2, 2, 2, 2};
  const int PL2[11] = {0, 1, 2, 0, 1, 1, 2, 0, 1, 2, 2};
  const int PLO[11] = {0, 1, 2, 1, 0, 2, 1, 2, 1, 0, 2};
  const int CGO[11] = {0, 1, 10, 35, 44, 53, 98, 143, 168, 213, 238};
  const double pw_io[3] = {sqrt(1.0 / 192.0), sqrt(3.0 / 256.0), sqrt(5.0 / 256.0)};
  for (int p = 0; p < 11; p++) {
    int l1 = PL1[p], l2 = PL2[p], lo = PLO[p];
    double c[5][5][5];
    cg_real(l1, l2, lo, c);
    double pw = pw_io[lo];
    for (int i = 0; i < 2 * l1 + 1; i++)
      for (int j = 0; j < 2 * l2 + 1; j++)
        for (int k = 0; k < 2 * lo + 1; k++)
          tab.v[CGO[p] + (i * (2 * l2 + 1) + j) * (2 * lo + 1) + k] = (float)(pw * c[i][j][k]);
  }
}

// ---------------- launch ----------------
extern "C" void kernel_launch(void* const* d_in, const int* in_sizes, int n_in,
                              void* d_out, int out_size, void* d_ws, size_t ws_size,
                              hipStream_t stream) {
  const float* x1 = (const float*)d_in[0];
  const float* x2 = (const float*)d_in[1];
  const float* W  = (const float*)d_in[2];
  float* out = (float*)d_out;

  int N = in_sizes[0] / NDIM1;  // 32768

  CGTab tab;
  build_cg_tables(tab);  // deterministic host-side computation, ~µs

  short8* wf = (short8*)d_ws;  // 11*2*4*64 * 16B = 90112 B

  hipLaunchKernelGGL(prep_w_kernel, dim3(22), dim3(256), 0, stream, W, wf);
  hipLaunchKernelGGL(TPWithWeights_44925357916441_kernel, dim3(N / 32), dim3(256), 0,
                     stream, x1, x2, wf, out, tab);
}

// Round 8
// 48.952 us; speedup vs baseline: 1.1140x; 1.0197x over previous
//
#include <hip/hip_runtime.h>
#include <hip/hip_bf16.h>

// ---------------- static problem config ----------------
#define NDIM1 576
#define NDIM2 9
#define NDIMO 576

typedef __attribute__((ext_vector_type(8))) short short8;
typedef __attribute__((ext_vector_type(4))) float f32x4;

union U8 { unsigned short s[8]; short8 v; };

__device__ inline unsigned short f2bf(float x) {
  return __builtin_bit_cast(unsigned short, __float2bfloat16(x));
}

// real-basis CG selection rule (superset of nonzeros):
constexpr bool cg_nonzero(int m1, int m2, int m3) {
  int a1 = m1 < 0 ? -m1 : m1, a2 = m2 < 0 ? -m2 : m2, a3 = m3 < 0 ? -m3 : m3;
  int d = a1 > a2 ? a1 - a2 : a2 - a1;
  bool mag = (a3 == a1 + a2) || (a3 == d);
  int neg = (m1 < 0) + (m2 < 0) + (m3 < 0);
  return mag && ((neg & 1) == 0);
}

// ================= compile-time CG tables (constexpr port of reference) ======
constexpr double cfact(int n) { double r = 1.0; for (int i = 2; i <= n; i++) r *= (double)i; return r; }
constexpr double csqrt_(double x) {
  if (x <= 0.0) return 0.0;
  double g = x < 1.0 ? 1.0 : x;
  for (int i = 0; i < 60; i++) g = 0.5 * (g + x / g);
  return g;
}
constexpr int cmax3(int a, int b, int c) { int m = a > b ? a : b; return m > c ? m : c; }
constexpr int cmin3(int a, int b, int c) { int m = a < b ? a : b; return m < c ? m : c; }

struct cpx { double re; double im; };
constexpr cpx operator*(cpx a, cpx b) { return {a.re * b.re - a.im * b.im, a.re * b.im + a.im * b.re}; }
constexpr cpx operator+(cpx a, cpx b) { return {a.re + b.re, a.im + b.im}; }
constexpr cpx cconj(cpx a) { return {a.re, -a.im}; }
constexpr cpx cscale(cpx a, double s) { return {a.re * s, a.im * s}; }

constexpr double su2_cg_c(int j1, int m1, int j2, int m2, int j3, int m3) {
  if (m3 != m1 + m2) return 0.0;
  int vmin = cmax3(-j1 + j2 + m3, -j1 + m1, 0);
  int vmax = cmin3(j2 + j3 + m1, j3 - j1 + j2, j3 + m3);
  double C = csqrt_((2.0 * j3 + 1.0) * cfact(j3 + j1 - j2) * cfact(j3 - j1 + j2) *
                    cfact(j1 + j2 - j3) * cfact(j3 + m3) * cfact(j3 - m3) /
                    (cfact(j1 + j2 + j3 + 1) * cfact(j1 - m1) * cfact(j1 + m1) *
                     cfact(j2 - m2) * cfact(j2 + m2)));
  double S = 0.0;
  for (int vv = vmin; vv <= vmax; vv++) {
    double sg = ((vv + j2 + m2) & 1) ? -1.0 : 1.0;
    S += sg * cfact(j2 + j3 + m1 - vv) * cfact(j1 - m1 + vv) /
         (cfact(vv) * cfact(j3 - j1 + j2 - vv) * cfact(j3 + m3 - vv) * cfact(vv + j1 - j2 - m3));
  }
  return C * S;
}

struct QM { cpx q[5][5]; };
constexpr QM cb_r2c_c(int l) {
  QM m{};
  const double is2 = 1.0 / csqrt_(2.0);
  for (int mm = -l; mm < 0; mm++) {
    m.q[l + mm][l - mm] = {is2, 0.0};
    m.q[l + mm][l + mm] = {0.0, -is2};
  }
  m.q[l][l] = {1.0, 0.0};
  for (int mm = 1; mm <= l; mm++) {
    double sg = (mm & 1) ? -1.0 : 1.0;
    m.q[l + mm][l + mm] = {sg * is2, 0.0};
    m.q[l + mm][l - mm] = {0.0, sg * is2};
  }
  cpx f{1.0, 0.0};
  for (int t = 0; t < l; t++) f = f * cpx{0.0, -1.0};
  for (int a = 0; a < 2 * l + 1; a++)
    for (int b = 0; b < 2 * l + 1; b++) m.q[a][b] = m.q[a][b] * f;
  return m;
}

struct C555 { double v[5][5][5]; };
constexpr C555 cg_real_c(int l1, int l2, int l3) {
  QM q1 = cb_r2c_c(l1), q2 = cb_r2c_c(l2), q3 = cb_r2c_c(l3);
  // precompute su2 table (cuts constexpr steps)
  double su[5][5][5]{};
  for (int i = 0; i < 2 * l1 + 1; i++)
    for (int k = 0; k < 2 * l2 + 1; k++)
      for (int n = 0; n < 2 * l3 + 1; n++)
        su[i][k][n] = su2_cg_c(l1, i - l1, l2, k - l2, l3, n - l3);
  C555 o{};
  double nrm = 0.0;
  for (int x = 0; x < 2 * l1 + 1; x++)
    for (int y = 0; y < 2 * l2 + 1; y++)
      for (int z = 0; z < 2 * l3 + 1; z++) {
        cpx a{0.0, 0.0};
        for (int i = 0; i < 2 * l1 + 1; i++)
          for (int k = 0; k < 2 * l2 + 1; k++)
            for (int n = 0; n < 2 * l3 + 1; n++) {
              double s = su[i][k][n];
              if (s != 0.0) a = a + cscale(q1.q[i][x] * q2.q[k][y] * cconj(q3.q[n][z]), s);
            }
        o.v[x][y][z] = a.re;
        nrm += a.re * a.re;
      }
  nrm = csqrt_(nrm);
  for (int x = 0; x < 2 * l1 + 1; x++)
    for (int y = 0; y < 2 * l2 + 1; y++)
      for (int z = 0; z < 2 * l3 + 1; z++) o.v[x][y][z] /= nrm;
  return o;
}

// one constexpr variable per path -> each evaluation stays under step limit
static constexpr C555 CGP0 = cg_real_c(0, 0, 0);
static constexpr C555 CGP1 = cg_real_c(0, 1, 1);
static constexpr C555 CGP2 = cg_real_c(0, 2, 2);
static constexpr C555 CGP3 = cg_real_c(1, 0, 1);
static constexpr C555 CGP4 = cg_real_c(1, 1, 0);
static constexpr C555 CGP5 = cg_real_c(1, 1, 2);
static constexpr C555 CGP6 = cg_real_c(1, 2, 1);
static constexpr C555 CGP7 = cg_real_c(2, 0, 2);
static constexpr C555 CGP8 = cg_real_c(2, 1, 1);
static constexpr C555 CGP9 = cg_real_c(2, 2, 0);
static constexpr C555 CGP10 = cg_real_c(2, 2, 2);

struct CGTabC { float v[363]; };
constexpr CGTabC build_flat() {
  CGTabC t{};
  const C555* cp[11] = {&CGP0, &CGP1, &CGP2, &CGP3, &CGP4, &CGP5, &CGP6, &CGP7, &CGP8, &CGP9, &CGP10};
  const int PL1[11] = {0, 0, 0, 1, 1, 1, 1, 2, 2, 2, 2};
  const int PL2[11] = {0, 1, 2, 0, 1, 1, 2, 0, 1, 2, 2};
  const int PLO[11] = {0, 1, 2, 1, 0, 2, 1, 2, 1, 0, 2};
  const int CGO[11] = {0, 1, 10, 35, 44, 53, 98, 143, 168, 213, 238};
  // path_normalization='element': pw depends only on output irrep
  const double pw_io[3] = {csqrt_(1.0 / 192.0), csqrt_(3.0 / 256.0), csqrt_(5.0 / 256.0)};
  for (int p = 0; p < 11; p++) {
    int l1 = PL1[p], l2 = PL2[p], lo = PLO[p];
    double pw = pw_io[lo];
    for (int i = 0; i < 2 * l1 + 1; i++)
      for (int j = 0; j < 2 * l2 + 1; j++)
        for (int k = 0; k < 2 * lo + 1; k++)
          t.v[CGO[p] + (i * (2 * l2 + 1) + j) * (2 * lo + 1) + k] = (float)(pw * cp[p]->v[i][j][k]);
  }
  return t;
}
static constexpr CGTabC CGT = build_flat();  // folds to inline literals in device code

// ---------------- prep kernel: pack W into bf16 MFMA B-fragments ----------------
__global__ __launch_bounds__(256) void prep_w_kernel(const float* __restrict__ W,
                                                     short8* __restrict__ wf) {
  int idx = blockIdx.x * 256 + threadIdx.x;
  if (idx >= 11 * 2 * 4 * 64) return;
  int lane = idx & 63;
  int v = (idx >> 6) & 3;
  int s = (idx >> 8) & 1;
  int p = idx >> 9;
  int g = lane >> 4, r16 = lane & 15;
  const float* wp = W + p * 4096 + (s * 32 + g * 8) * 64 + v * 16 + r16;
  U8 u;
#pragma unroll
  for (int t = 0; t < 8; t++) u.s[t] = f2bf(wp[t * 64]);
  wf[idx] = u.v;
}

// ---------------- staging: global f32 -> registers (issue-early) ----------------
// wave roles: wv0 = chunk0 (c0), wv1 = chunk1 (c1), wv2/wv3 = chunk2 s=0/1.
__device__ __forceinline__ void stage_issue(const float* __restrict__ x1, int nt,
                                            int wv, int g, int r16, f32x4 (&raw)[12]) {
  const float* row = x1 + (size_t)(nt * 16 + r16) * NDIM1;
  if (wv == 0) {
#pragma unroll
    for (int s = 0; s < 2; s++) {
      const f32x4* p = (const f32x4*)(row + (s * 32 + g * 8));
      raw[s * 2 + 0] = p[0];
      raw[s * 2 + 1] = p[1];
    }
  } else if (wv == 1) {
#pragma unroll
    for (int s = 0; s < 2; s++) {
      const f32x4* p = (const f32x4*)(row + 64 + (s * 32 + g * 8) * 3);
#pragma unroll
      for (int q = 0; q < 6; q++) raw[s * 6 + q] = p[q];
    }
  } else {
    const int s = wv - 2;
    const f32x4* p = (const f32x4*)(row + 256 + (s * 32 + g * 8) * 5);
#pragma unroll
    for (int q = 0; q < 10; q++) raw[q] = p[q];
  }
}

__device__ __forceinline__ void stage_write(short8 (*fb)[64], int wv, int lane,
                                            const f32x4 (&raw)[12]) {
  const float* rf = (const float*)raw;
  if (wv == 0) {
#pragma unroll
    for (int s = 0; s < 2; s++) {
      U8 u;
#pragma unroll
      for (int t = 0; t < 8; t++) u.s[t] = f2bf(rf[s * 8 + t]);
      fb[s][lane] = u.v;
    }
  } else if (wv == 1) {
#pragma unroll
    for (int s = 0; s < 2; s++)
#pragma unroll
      for (int i = 0; i < 3; i++) {
        U8 u;
#pragma unroll
        for (int t = 0; t < 8; t++) u.s[t] = f2bf(rf[s * 24 + t * 3 + i]);
        fb[2 + s * 3 + i][lane] = u.v;
      }
  } else {
    const int s = wv - 2;
#pragma unroll
    for (int i = 0; i < 5; i++) {
      U8 u;
#pragma unroll
      for (int t = 0; t < 8; t++) u.s[t] = f2bf(rf[t * 5 + i]);
      fb[8 + s * 5 + i][lane] = u.v;
    }
  }
}

// ---------------- MFMA + epilogue ----------------
template <int NI>
__device__ __forceinline__ void run_path(const short8* __restrict__ wf, int p, int v, int lane,
                                         const short8 (&af)[NI][2], f32x4 (&acc)[NI]) {
#pragma unroll
  for (int i = 0; i < NI; i++) acc[i] = (f32x4){0.f, 0.f, 0.f, 0.f};
#pragma unroll
  for (int s = 0; s < 2; s++) {
    short8 b = wf[((p * 2 + s) * 4 + v) * 64 + lane];
#pragma unroll
    for (int i = 0; i < NI; i++)
      acc[i] = __builtin_amdgcn_mfma_f32_16x16x32_bf16(af[i][s], b, acc[i], 0, 0, 0);
  }
}

template <int L1, int L2, int LO, int CGO, int NI>
__device__ __forceinline__ void epilogue(const f32x4 (&acc)[NI],
                                         const float (&x2v)[4][9], float (&outr)[4][9]) {
  constexpr int JO = (L2 == 0) ? 0 : (L2 == 1 ? 1 : 4);
  constexpr int KO = (LO == 0) ? 0 : (LO == 1 ? 1 : 4);
#pragma unroll
  for (int i = 0; i < 2 * L1 + 1; i++) {
#pragma unroll
    for (int j = 0; j < 2 * L2 + 1; j++) {
#pragma unroll
      for (int k = 0; k < 2 * LO + 1; k++) {
        if (!cg_nonzero(i - L1, j - L2, k - LO)) continue;  // folds after unroll
        // constexpr table + constant index -> folded to an inline literal
        float c = CGT.v[CGO + (i * (2 * L2 + 1) + j) * (2 * LO + 1) + k];
#pragma unroll
        for (int r = 0; r < 4; r++)
          outr[r][KO + k] = fmaf(c * x2v[r][JO + j], acc[i][r], outr[r][KO + k]);
      }
    }
  }
}

// full compute for one 16-row tile from a staged bf16-frag buffer
__device__ __forceinline__ void compute_tile(const short8 (*fb)[64],
                                             const float* __restrict__ x2,
                                             const short8* __restrict__ wf,
                                             float* __restrict__ out,
                                             int n0, int v, int lane, int g, int r16) {
  f32x4 xv[9];
  {
    const f32x4* p2 = (const f32x4*)(x2 + (size_t)(n0 + g * 4) * NDIM2);
#pragma unroll
    for (int q = 0; q < 9; q++) xv[q] = p2[q];
  }
  float x2v[4][9];
  float outr[4][9];
#pragma unroll
  for (int r = 0; r < 4; r++)
#pragma unroll
    for (int j = 0; j < 9; j++) {
      int idx = r * 9 + j;
      x2v[r][j] = xv[idx >> 2][idx & 3];
      outr[r][j] = 0.f;
    }

  {  // chunk0 (l1=0), paths 0..2
    short8 af[1][2]; f32x4 acc[1];
#pragma unroll
    for (int s = 0; s < 2; s++) af[0][s] = fb[s][lane];
    run_path<1>(wf, 0, v, lane, af, acc); epilogue<0, 0, 0, 0, 1>(acc, x2v, outr);
    run_path<1>(wf, 1, v, lane, af, acc); epilogue<0, 1, 1, 1, 1>(acc, x2v, outr);
    run_path<1>(wf, 2, v, lane, af, acc); epilogue<0, 2, 2, 10, 1>(acc, x2v, outr);
  }
  {  // chunk1 (l1=1), paths 3..6
    short8 af[3][2]; f32x4 acc[3];
#pragma unroll
    for (int s = 0; s < 2; s++)
#pragma unroll
      for (int i = 0; i < 3; i++) af[i][s] = fb[2 + s * 3 + i][lane];
    run_path<3>(wf, 3, v, lane, af, acc); epilogue<1, 0, 1, 35, 3>(acc, x2v, outr);
    run_path<3>(wf, 4, v, lane, af, acc); epilogue<1, 1, 0, 44, 3>(acc, x2v, outr);
    run_path<3>(wf, 5, v, lane, af, acc); epilogue<1, 1, 2, 53, 3>(acc, x2v, outr);
    run_path<3>(wf, 6, v, lane, af, acc); epilogue<1, 2, 1, 98, 3>(acc, x2v, outr);
  }
  {  // chunk2 (l1=2), paths 7..10
    short8 af[5][2]; f32x4 acc[5];
#pragma unroll
    for (int s = 0; s < 2; s++)
#pragma unroll
      for (int i = 0; i < 5; i++) af[i][s] = fb[8 + s * 5 + i][lane];
    run_path<5>(wf, 7, v, lane, af, acc); epilogue<2, 0, 2, 143, 5>(acc, x2v, outr);
    run_path<5>(wf, 8, v, lane, af, acc); epilogue<2, 1, 1, 168, 5>(acc, x2v, outr);
    run_path<5>(wf, 9, v, lane, af, acc); epilogue<2, 2, 0, 213, 5>(acc, x2v, outr);
    run_path<5>(wf, 10, v, lane, af, acc); epilogue<2, 2, 2, 238, 5>(acc, x2v, outr);
  }

  const int w = v * 16 + r16;
#pragma unroll
  for (int r = 0; r < 4; r++) {
    float* op = out + (size_t)(n0 + g * 4 + r) * NDIMO;
    op[w] = outr[r][0];
#pragma unroll
    for (int k = 0; k < 3; k++) op[64 + w * 3 + k] = outr[r][1 + k];
#pragma unroll
    for (int k = 0; k < 5; k++) op[256 + w * 5 + k] = outr[r][4 + k];
  }
}

// ---------------- main kernel ----------------
// Block = 2 tiles of 16 rows, 4 waves. Reg-stage f32 -> bf16 frags into LDS
// (convert once per element). Double buffer 2 x 18.4 KB. T14 split: issue
// tile-1 loads early, compute tile 0, write tile-1 frags late.
__global__ __launch_bounds__(256) void TPWithWeights_44925357916441_kernel(
    const float* __restrict__ x1, const float* __restrict__ x2,
    const short8* __restrict__ wf, float* __restrict__ out) {
  __shared__ short8 frg[2][18][64];

  const int lane = threadIdx.x & 63;
  const int wv = threadIdx.x >> 6;   // wave id: staging role AND w sub-tile v
  const int g = lane >> 4, r16 = lane & 15;
  const int t0 = blockIdx.x * 2;

  {
    f32x4 rawA[12];
    stage_issue(x1, t0, wv, g, r16, rawA);
    stage_write(frg[0], wv, lane, rawA);
  }
  __syncthreads();

  {
    f32x4 rawB[12];
    stage_issue(x1, t0 + 1, wv, g, r16, rawB);
    compute_tile(frg[0], x2, wf, out, t0 << 4, wv, lane, g, r16);
    stage_write(frg[1], wv, lane, rawB);
  }
  __syncthreads();

  compute_tile(frg[1], x2, wf, out, (t0 + 1) << 4, wv, lane, g, r16);
}

// ---------------- launch ----------------
extern "C" void kernel_launch(void* const* d_in, const int* in_sizes, int n_in,
                              void* d_out, int out_size, void* d_ws, size_t ws_size,
                              hipStream_t stream) {
  const float* x1 = (const float*)d_in[0];
  const float* x2 = (const float*)d_in[1];
  const float* W  = (const float*)d_in[2];
  float* out = (float*)d_out;

  int N = in_sizes[0] / NDIM1;  // 32768

  short8* wf = (short8*)d_ws;  // 11*2*4*64 * 16B = 90112 B

  hipLaunchKernelGGL(prep_w_kernel, dim3(22), dim3(256), 0, stream, W, wf);
  hipLaunchKernelGGL(TPWithWeights_44925357916441_kernel, dim3(N / 32), dim3(256), 0,
                     stream, x1, x2, wf, out);
}